// Round 1
// baseline (856.716 us; speedup 1.0000x reference)
//
#include <hip/hip_runtime.h>

#define NN 100000
#define NE 1600000
#define NG 64
#define NB_SCAN 98  // ceil(NN/1024)

__device__ __forceinline__ float silu_f(float x) { return x / (1.0f + __expf(-x)); }

// ---- degree (weighted, + self loop added later) and edge count histogram ----
__global__ void k_deg_cnt(const int* __restrict__ col, const float* __restrict__ ew,
                          float* __restrict__ deg, int* __restrict__ cnt) {
  int e = blockIdx.x * 256 + threadIdx.x;
  if (e < NE) {
    int c = col[e];
    atomicAdd(&deg[c], ew[e]);
    atomicAdd(&cnt[c], 1);
  }
}

__global__ void k_dinv(float* __restrict__ deg) {
  int i = blockIdx.x * 256 + threadIdx.x;
  if (i < NN) deg[i] = rsqrtf(deg[i] + 1.0f);  // +1 = self-loop weight; deg>0 always
}

// ---- exclusive scan over cnt -> off (3-kernel hierarchical) ----
__global__ void k_scanA(const int* __restrict__ cnt, int* __restrict__ off,
                        int* __restrict__ bsum) {
  __shared__ int sm[1024];
  int i = blockIdx.x * 1024 + threadIdx.x;
  int v = (i < NN) ? cnt[i] : 0;
  sm[threadIdx.x] = v;
  __syncthreads();
  for (int s = 1; s < 1024; s <<= 1) {
    int t = (threadIdx.x >= (unsigned)s) ? sm[threadIdx.x - s] : 0;
    __syncthreads();
    sm[threadIdx.x] += t;
    __syncthreads();
  }
  if (i < NN) off[i] = sm[threadIdx.x] - v;
  if (threadIdx.x == 1023) bsum[blockIdx.x] = sm[1023];
}

__global__ void k_scanB(const int* __restrict__ bsum, int* __restrict__ bbase,
                        int* __restrict__ off) {
  __shared__ int sm[128];
  int t = threadIdx.x;
  int v = (t < NB_SCAN) ? bsum[t] : 0;
  sm[t] = v;
  __syncthreads();
  for (int s = 1; s < 128; s <<= 1) {
    int u = (t >= s) ? sm[t - s] : 0;
    __syncthreads();
    sm[t] += u;
    __syncthreads();
  }
  if (t < NB_SCAN) bbase[t] = sm[t] - v;
  if (t == 127) off[NN] = sm[127];
}

__global__ void k_scanC(int* __restrict__ off, int* __restrict__ cur,
                        const int* __restrict__ bbase) {
  int i = blockIdx.x * 1024 + threadIdx.x;
  if (i < NN) {
    int v = off[i] + bbase[blockIdx.x];
    off[i] = v;
    cur[i] = v;
  }
}

// ---- CSR fill: bucket edges by target, precompute norm coefficient ----
__global__ void k_fill(const int* __restrict__ row, const int* __restrict__ col,
                       const float* __restrict__ ew, const float* __restrict__ dinv,
                       int* __restrict__ cur, int* __restrict__ erow,
                       float* __restrict__ ecoef) {
  int e = blockIdx.x * 256 + threadIdx.x;
  if (e < NE) {
    int r = row[e], c = col[e];
    int p = atomicAdd(&cur[c], 1);
    erow[p] = r;
    ecoef[p] = dinv[r] * ew[e] * dinv[c];
  }
}

// ---- h1 = x @ W1  (N x 3  *  3 x 100) ----
__global__ void k_h1(const float* __restrict__ x, const float* __restrict__ W1,
                     float* __restrict__ h1) {
  int t = blockIdx.x * 256 + threadIdx.x;
  if (t >= NN * 25) return;
  int n = t / 25, q = t % 25;
  float x0 = x[n * 3 + 0], x1 = x[n * 3 + 1], x2 = x[n * 3 + 2];
  float4 w0 = ((const float4*)(W1))[q];
  float4 w1 = ((const float4*)(W1 + 100))[q];
  float4 w2 = ((const float4*)(W1 + 200))[q];
  float4 o;
  o.x = x0 * w0.x + x1 * w1.x + x2 * w2.x;
  o.y = x0 * w0.y + x1 * w1.y + x2 * w2.y;
  o.z = x0 * w0.z + x1 * w1.z + x2 * w2.z;
  o.w = x0 * w0.w + x1 * w1.w + x2 * w2.w;
  ((float4*)h1)[t] = o;
}

// ---- aggregation layer 1 (dim 100), fused bias + SiLU. One wave per node. ----
__global__ void k_agg1(const float* __restrict__ h, const float* __restrict__ dinv,
                       const int* __restrict__ off, const int* __restrict__ erow,
                       const float* __restrict__ ecoef, const float* __restrict__ b1,
                       float* __restrict__ z1) {
  int wave = threadIdx.x >> 6;
  int lane = threadIdx.x & 63;
  int c = blockIdx.x * 4 + wave;
  if (c >= NN) return;
  float di = dinv[c];
  float s = di * di;  // self-loop norm
  const float* hc = h + (size_t)c * 100;
  float a0 = s * hc[lane];
  float a1 = (lane < 36) ? s * hc[lane + 64] : 0.0f;
  int lo = off[c], hi = off[c + 1];
  for (int p = lo; p < hi; ++p) {
    int r = erow[p];
    float cf = ecoef[p];
    const float* hr = h + (size_t)r * 100;
    a0 += cf * hr[lane];
    if (lane < 36) a1 += cf * hr[lane + 64];
  }
  float* zc = z1 + (size_t)c * 100;
  zc[lane] = silu_f(a0 + b1[lane]);
  if (lane < 36) zc[lane + 64] = silu_f(a1 + b1[lane + 64]);
}

// ---- h2 = z1 @ W2  (N x 100 * 100 x 200), 20 nodes/block, z1 tile in LDS ----
__global__ void k_h2(const float* __restrict__ z1, const float* __restrict__ W2,
                     float* __restrict__ h2) {
  __shared__ float zs[20][100];
  int nb = blockIdx.x * 20;
  for (int i = threadIdx.x; i < 2000; i += 256) {
    int nn = i / 100, kk = i % 100;
    zs[nn][kk] = z1[(size_t)(nb + nn) * 100 + kk];
  }
  __syncthreads();
  int q = threadIdx.x % 50;  // float4 column group over 200 dims
  int r = threadIdx.x / 50;  // node quad
  if (r >= 5) return;
  float4 a0 = {0, 0, 0, 0}, a1 = {0, 0, 0, 0}, a2 = {0, 0, 0, 0}, a3 = {0, 0, 0, 0};
  const float4* W2v = (const float4*)W2;
  int n0 = r * 4;
  for (int k = 0; k < 100; ++k) {
    float4 w = W2v[k * 50 + q];
    float v0 = zs[n0 + 0][k], v1 = zs[n0 + 1][k], v2 = zs[n0 + 2][k], v3 = zs[n0 + 3][k];
    a0.x += v0 * w.x; a0.y += v0 * w.y; a0.z += v0 * w.z; a0.w += v0 * w.w;
    a1.x += v1 * w.x; a1.y += v1 * w.y; a1.z += v1 * w.z; a1.w += v1 * w.w;
    a2.x += v2 * w.x; a2.y += v2 * w.y; a2.z += v2 * w.z; a2.w += v2 * w.w;
    a3.x += v3 * w.x; a3.y += v3 * w.y; a3.z += v3 * w.z; a3.w += v3 * w.w;
  }
  float4* out = (float4*)h2;
  out[(size_t)(nb + n0 + 0) * 50 + q] = a0;
  out[(size_t)(nb + n0 + 1) * 50 + q] = a1;
  out[(size_t)(nb + n0 + 2) * 50 + q] = a2;
  out[(size_t)(nb + n0 + 3) * 50 + q] = a3;
}

// ---- aggregation layer 2 (dim 200), fused bias + SiLU -> z2 ----
__global__ void k_agg2(const float* __restrict__ h, const float* __restrict__ dinv,
                       const int* __restrict__ off, const int* __restrict__ erow,
                       const float* __restrict__ ecoef, const float* __restrict__ b2,
                       float* __restrict__ z2) {
  int wave = threadIdx.x >> 6;
  int lane = threadIdx.x & 63;
  int c = blockIdx.x * 4 + wave;
  if (c >= NN) return;
  float di = dinv[c];
  float s = di * di;
  const float* hc = h + (size_t)c * 200;
  float a0 = s * hc[lane];
  float a1 = s * hc[lane + 64];
  float a2 = s * hc[lane + 128];
  float a3 = (lane < 8) ? s * hc[lane + 192] : 0.0f;
  int lo = off[c], hi = off[c + 1];
  for (int p = lo; p < hi; ++p) {
    int r = erow[p];
    float cf = ecoef[p];
    const float* hr = h + (size_t)r * 200;
    a0 += cf * hr[lane];
    a1 += cf * hr[lane + 64];
    a2 += cf * hr[lane + 128];
    if (lane < 8) a3 += cf * hr[lane + 192];
  }
  float* zc = z2 + (size_t)c * 200;
  zc[lane] = silu_f(a0 + b2[lane]);
  zc[lane + 64] = silu_f(a1 + b2[lane + 64]);
  zc[lane + 128] = silu_f(a2 + b2[lane + 128]);
  if (lane < 8) zc[lane + 192] = silu_f(a3 + b2[lane + 192]);
}

// ---- graph start offsets via binary search on sorted batch ----
__global__ void k_gstart(const int* __restrict__ batch, int* __restrict__ gstart) {
  int g = threadIdx.x;
  if (g > NG) return;
  int lo = 0, hi = NN;
  while (lo < hi) {
    int mid = (lo + hi) >> 1;
    if (batch[mid] < g) lo = mid + 1; else hi = mid;
  }
  gstart[g] = lo;
}

// ---- pooling: 16 slices per graph, per-block register accumulate, 1 atomic/dim ----
__global__ void k_pool(const float* __restrict__ z2, const int* __restrict__ gstart,
                       float* __restrict__ pooled) {
  int g = blockIdx.x >> 4;
  int sl = blockIdx.x & 15;
  int lo = gstart[g], hi = gstart[g + 1];
  int len = hi - lo;
  if (len <= 0) return;
  int chunk = (len + 15) >> 4;
  int a = lo + sl * chunk;
  int e = min(a + chunk, hi);
  int t = threadIdx.x;
  if (t >= 200 || a >= e) return;
  float acc = 0.0f;
  for (int n = a; n < e; ++n) acc += z2[(size_t)n * 200 + t];
  atomicAdd(&pooled[g * 200 + t], acc);
}

// ---- head: mean, silu(pooled@Wl1+bl1) @ Wl2 + bl2 ----
__global__ void k_final(const float* __restrict__ pooled, const int* __restrict__ gstart,
                        const float* __restrict__ Wl1, const float* __restrict__ bl1,
                        const float* __restrict__ Wl2, const float* __restrict__ bl2,
                        float* __restrict__ out) {
  __shared__ float hid[100];
  int g = blockIdx.x;
  int cntg = gstart[g + 1] - gstart[g];
  float inv = 1.0f / (float)((cntg > 0) ? cntg : 1);
  int j = threadIdx.x;
  if (j < 100) {
    float a = bl1[j];
    for (int k = 0; k < 200; ++k) a += (pooled[g * 200 + k] * inv) * Wl1[k * 100 + j];
    a = silu_f(a);
    hid[j] = a * Wl2[j];
  }
  __syncthreads();
  if (j == 0) {
    float sum = bl2[0];
    for (int k = 0; k < 100; ++k) sum += hid[k];
    out[g] = sum;
  }
}

extern "C" void kernel_launch(void* const* d_in, const int* in_sizes, int n_in,
                              void* d_out, int out_size, void* d_ws, size_t ws_size,
                              hipStream_t stream) {
  const float* x   = (const float*)d_in[0];
  const float* ew  = (const float*)d_in[1];
  const float* W1  = (const float*)d_in[2];
  const float* b1  = (const float*)d_in[3];
  const float* W2  = (const float*)d_in[4];
  const float* b2  = (const float*)d_in[5];
  const float* Wl1 = (const float*)d_in[6];
  const float* bl1 = (const float*)d_in[7];
  const float* Wl2 = (const float*)d_in[8];
  const float* bl2 = (const float*)d_in[9];
  const int* ei    = (const int*)d_in[10];
  const int* batch = (const int*)d_in[11];
  const int* rowp = ei;            // edge_index[0] = sources
  const int* colp = ei + NE;       // edge_index[1] = targets
  float* out = (float*)d_out;

  char* w = (char*)d_ws;
  size_t o = 0;
  auto alloc = [&](size_t bytes) {
    char* p = w + o;
    o = (o + bytes + 255) & ~(size_t)255;
    return p;
  };
  float* deg    = (float*)alloc((size_t)NN * 4);        // becomes dinv in-place
  int*   cnt    = (int*)alloc((size_t)NN * 4);
  int*   off    = (int*)alloc((size_t)(NN + 1) * 4);
  int*   cur    = (int*)alloc((size_t)NN * 4);
  int*   bsum   = (int*)alloc((size_t)NB_SCAN * 4);
  int*   bbase  = (int*)alloc((size_t)NB_SCAN * 4);
  int*   erow   = (int*)alloc((size_t)NE * 4);
  float* ecoef  = (float*)alloc((size_t)NE * 4);
  int*   gstart = (int*)alloc((size_t)(NG + 1) * 4);
  float* pooled = (float*)alloc((size_t)NG * 200 * 4);
  // node feature buffers: h1[40MB] z1[40MB] h2[80MB]; z2 reuses h1+z1 span
  char* nbase = alloc((size_t)NN * 400 * 4);  // 160 MB
  float* h1 = (float*)nbase;
  float* z1 = (float*)(nbase + (size_t)NN * 100 * 4);
  float* h2 = (float*)(nbase + (size_t)NN * 200 * 4);
  float* z2 = (float*)nbase;  // h1,z1 dead by the time z2 is written

  hipMemsetAsync(deg, 0, (size_t)NN * 4, stream);
  hipMemsetAsync(cnt, 0, (size_t)NN * 4, stream);
  hipMemsetAsync(pooled, 0, (size_t)NG * 200 * 4, stream);

  k_deg_cnt<<<(NE + 255) / 256, 256, 0, stream>>>(colp, ew, deg, cnt);
  k_dinv<<<(NN + 255) / 256, 256, 0, stream>>>(deg);
  k_scanA<<<NB_SCAN, 1024, 0, stream>>>(cnt, off, bsum);
  k_scanB<<<1, 128, 0, stream>>>(bsum, bbase, off);
  k_scanC<<<NB_SCAN, 1024, 0, stream>>>(off, cur, bbase);
  k_fill<<<(NE + 255) / 256, 256, 0, stream>>>(rowp, colp, ew, deg, cur, erow, ecoef);
  k_h1<<<(NN * 25 + 255) / 256, 256, 0, stream>>>(x, W1, h1);
  k_agg1<<<(NN + 3) / 4, 256, 0, stream>>>(h1, deg, off, erow, ecoef, b1, z1);
  k_h2<<<NN / 20, 256, 0, stream>>>(z1, W2, h2);
  k_agg2<<<(NN + 3) / 4, 256, 0, stream>>>(h2, deg, off, erow, ecoef, b2, z2);
  k_gstart<<<1, 128, 0, stream>>>(batch, gstart);
  k_pool<<<NG * 16, 256, 0, stream>>>(z2, gstart, pooled);
  k_final<<<NG, 128, 0, stream>>>(pooled, gstart, Wl1, bl1, Wl2, bl2, out);
}